// Round 10
// baseline (627.404 us; speedup 1.0000x reference)
//
#include <hip/hip_runtime.h>
#include <cstdint>
#include <cstddef>

#define B_ 4
#define T_ 2048
#define C_ 768
#define H_ 12
#define D_ 64
#define M_ (B_*T_)      // 8192
#define C3_ 2304
#define HID_ 3072

typedef unsigned short ushort_t;
typedef __bf16 bf16x8_t __attribute__((ext_vector_type(8)));
typedef short short4_t __attribute__((ext_vector_type(4)));
typedef float f32x4 __attribute__((ext_vector_type(4)));

typedef const __attribute__((address_space(1))) void* gas_ptr;
typedef __attribute__((address_space(3))) void* las_ptr;

__device__ __forceinline__ void gload_lds16(const ushort_t* g, ushort_t* l) {
  __builtin_amdgcn_global_load_lds((gas_ptr)g, (las_ptr)l, 16, 0, 0);
}

__device__ __forceinline__ float bf2f(ushort_t h) {
  union { unsigned int u; float f; } cv; cv.u = ((unsigned int)h) << 16; return cv.f;
}
__device__ __forceinline__ ushort_t f2bf(float f) {
  union { float f; unsigned int u; } cv; cv.f = f;
  unsigned int u = cv.u;
  unsigned int r = (u + 0x7FFFu + ((u >> 16) & 1u)) >> 16;
  return (ushort_t)r;
}
__device__ __forceinline__ short f2bf_trunc_s(float f) {   // RTZ, for P in (0,1]
  union { float f; unsigned int u; } cv; cv.f = f;
  return (short)(cv.u >> 16);
}

// ---------------- transpose+cast W[K,N] f32 -> Wt[N,K] bf16 ----------------
__global__ __launch_bounds__(256) void transpose_k(const float* __restrict__ in,
                                                   ushort_t* __restrict__ out, int K, int N) {
  __shared__ ushort_t tile[32][33];
  int nx = threadIdx.x, ky = threadIdx.y;           // block (32,8)
  int n0 = blockIdx.x * 32, k0 = blockIdx.y * 32;
#pragma unroll
  for (int i = 0; i < 4; i++)
    tile[ky + i * 8][nx] = f2bf(in[(size_t)(k0 + ky + i * 8) * N + n0 + nx]);
  __syncthreads();
#pragma unroll
  for (int i = 0; i < 4; i++)
    out[(size_t)(n0 + ky + i * 8) * K + k0 + nx] = tile[nx][ky + i * 8];
}

// ---------------- V transpose: qkv V-part [t][d] -> Vg[bh][d][t] ----------------
__global__ __launch_bounds__(256) void vtrans_k(const ushort_t* __restrict__ qkv,
                                                ushort_t* __restrict__ vg) {
  __shared__ ushort_t tile[32][33];
  int nx = threadIdx.x, ky = threadIdx.y;           // block (32,8)
  int t0 = blockIdx.x * 32, d0 = blockIdx.y * 32;
  int bh = blockIdx.z;
  int b = bh / H_, h = bh % H_;
  const ushort_t* src = qkv + (size_t)b * T_ * C3_ + 2 * C_ + h * D_;
#pragma unroll
  for (int i = 0; i < 4; i++)
    tile[ky + i * 8][nx] = src[(size_t)(t0 + ky + i * 8) * C3_ + d0 + nx];
  __syncthreads();
  ushort_t* dst = vg + (size_t)bh * D_ * T_;
#pragma unroll
  for (int i = 0; i < 4; i++)
    dst[(size_t)(d0 + ky + i * 8) * T_ + t0 + nx] = tile[nx][ky + i * 8];
}

// ---------------- layernorm (row = 768), f32 in -> bf16 out ----------------
__global__ __launch_bounds__(256) void ln_k(const float* __restrict__ x, const float* __restrict__ g,
                                            const float* __restrict__ bb, ushort_t* __restrict__ out) {
  __shared__ float red[8];
  int row = blockIdx.x, t = threadIdx.x;
  const float* xr = x + (size_t)row * C_;
  float v0 = xr[t], v1 = xr[t + 256], v2 = xr[t + 512];
  float s = v0 + v1 + v2;
  float s2 = v0 * v0 + v1 * v1 + v2 * v2;
#pragma unroll
  for (int m = 32; m >= 1; m >>= 1) { s += __shfl_xor(s, m); s2 += __shfl_xor(s2, m); }
  int w = t >> 6;
  if ((t & 63) == 0) { red[w * 2] = s; red[w * 2 + 1] = s2; }
  __syncthreads();
  s = red[0] + red[2] + red[4] + red[6];
  s2 = red[1] + red[3] + red[5] + red[7];
  float mu = s * (1.f / C_);
  float var = s2 * (1.f / C_) - mu * mu;
  float rstd = rsqrtf(var + 1e-5f);
  out[(size_t)row * C_ + t]       = f2bf((v0 - mu) * rstd * g[t] + bb[t]);
  out[(size_t)row * C_ + t + 256] = f2bf((v1 - mu) * rstd * g[t + 256] + bb[t + 256]);
  out[(size_t)row * C_ + t + 512] = f2bf((v2 - mu) * rstd * g[t + 512] + bb[t + 512]);
}

// ---------------- GEMM: C[M,N] = A[M,K] @ Bt[N,K]^T, fused epilogues ----------------
#define MFMA16(d, a, b) d = __builtin_amdgcn_mfma_f32_16x16x32_bf16(a, b, d, 0, 0, 0)
#define MFMA16K16(d, a, b) d = __builtin_amdgcn_mfma_f32_16x16x16bf16_1k(a, b, d, 0, 0, 0)

template <int EPI>
__global__ void gemm_bt_k(const ushort_t* __restrict__ A,
                          const ushort_t* __restrict__ Bt,
                          const float* __restrict__ res,
                          void* __restrict__ outp,
                          int N, int K) {
  __shared__ __align__(16) ushort_t As[128][32];
  __shared__ __align__(16) ushort_t Bs[128][32];
  int t = threadIdx.x;
  int bn = blockIdx.x * 128, bm = blockIdx.y * 128;
  int lane = t & 63, w = t >> 6;
  int wm = (w >> 1) * 64, wn = (w & 1) * 64;
  int lm = lane & 15, q8 = (lane >> 4) * 8;

  int lr = lane >> 2, lc = (lane & 3) * 8;
  const ushort_t* ga0 = A  + (size_t)(bm + w * 16 + lr) * K + lc;
  const ushort_t* gb0 = Bt + (size_t)(bn + w * 16 + lr) * K + lc;
  const size_t kstep64 = (size_t)64 * K;
  ushort_t* la0 = &As[w * 16][0];
  ushort_t* la1 = &As[w * 16 + 64][0];
  ushort_t* lb0 = &Bs[w * 16][0];
  ushort_t* lb1 = &Bs[w * 16 + 64][0];

  const f32x4 fz = {0.f, 0.f, 0.f, 0.f};
  f32x4 acc00 = fz, acc01 = fz, acc02 = fz, acc03 = fz;
  f32x4 acc10 = fz, acc11 = fz, acc12 = fz, acc13 = fz;
  f32x4 acc20 = fz, acc21 = fz, acc22 = fz, acc23 = fz;
  f32x4 acc30 = fz, acc31 = fz, acc32 = fz, acc33 = fz;

  for (int k0 = 0; k0 < K; k0 += 32) {
    __syncthreads();
    gload_lds16(ga0 + k0, la0);
    gload_lds16(ga0 + kstep64 + k0, la1);
    gload_lds16(gb0 + k0, lb0);
    gload_lds16(gb0 + kstep64 + k0, lb1);
    __syncthreads();   // drains vmcnt -> staged data visible
    bf16x8_t af0 = *(const bf16x8_t*)&As[wm + lm][q8];
    bf16x8_t af1 = *(const bf16x8_t*)&As[wm + 16 + lm][q8];
    bf16x8_t af2 = *(const bf16x8_t*)&As[wm + 32 + lm][q8];
    bf16x8_t af3 = *(const bf16x8_t*)&As[wm + 48 + lm][q8];
    bf16x8_t bg0 = *(const bf16x8_t*)&Bs[wn + lm][q8];
    bf16x8_t bg1 = *(const bf16x8_t*)&Bs[wn + 16 + lm][q8];
    bf16x8_t bg2 = *(const bf16x8_t*)&Bs[wn + 32 + lm][q8];
    bf16x8_t bg3 = *(const bf16x8_t*)&Bs[wn + 48 + lm][q8];
    MFMA16(acc00, af0, bg0); MFMA16(acc01, af0, bg1); MFMA16(acc02, af0, bg2); MFMA16(acc03, af0, bg3);
    MFMA16(acc10, af1, bg0); MFMA16(acc11, af1, bg1); MFMA16(acc12, af1, bg2); MFMA16(acc13, af1, bg3);
    MFMA16(acc20, af2, bg0); MFMA16(acc21, af2, bg1); MFMA16(acc22, af2, bg2); MFMA16(acc23, af2, bg3);
    MFMA16(acc30, af3, bg0); MFMA16(acc31, af3, bg1); MFMA16(acc32, af3, bg2); MFMA16(acc33, af3, bg3);
  }

  int rowb = bm + wm + (lane >> 4) * 4;
  int colb = bn + wn + lm;

#define ST(vv, row, jj) do { \
    float v = (vv); \
    size_t idx = (size_t)(row) * N + colb + (jj) * 16; \
    if constexpr (EPI == 0) { ((ushort_t*)outp)[idx] = f2bf(v); } \
    else if constexpr (EPI == 1) { ((float*)outp)[idx] = v + res[idx]; } \
    else { float gl = 0.5f * v * (1.0f + erff(v * 0.70710678118654752f)); \
           ((ushort_t*)outp)[idx] = f2bf(gl); } \
  } while (0)
#define STROW(a0, a1, a2, a3, row, rr) \
    ST(a0[rr], row, 0); ST(a1[rr], row, 1); ST(a2[rr], row, 2); ST(a3[rr], row, 3);
#define STBLK(a0, a1, a2, a3, rbase) \
    STROW(a0, a1, a2, a3, (rbase), 0) STROW(a0, a1, a2, a3, (rbase) + 1, 1) \
    STROW(a0, a1, a2, a3, (rbase) + 2, 2) STROW(a0, a1, a2, a3, (rbase) + 3, 3)

  STBLK(acc00, acc01, acc02, acc03, rowb)
  STBLK(acc10, acc11, acc12, acc13, rowb + 16)
  STBLK(acc20, acc21, acc22, acc23, rowb + 32)
  STBLK(acc30, acc31, acc32, acc33, rowb + 48)
#undef ST
#undef STROW
#undef STBLK
}

// ---------------- flash attention (causal): S^T formulation, zero LDS ----------------
// S^T = K*Q^T via mfma_16x16x32 (A=K-frag, B=Q-frag). S^T's C-layout
// (row=k=quad*4+reg, col=q=lane&15) IS the B-operand layout of
// mfma_16x16x16 (k=quad*4+j, n=lane&15), so exp2(S^T) feeds O^T = V^T * P^T
// directly from registers -- no LDS transpose, no barriers, no DS ops.
// lsum is one scalar per lane (lane owns one q); 2 shuffles at the end.
__global__ __launch_bounds__(256, 3) void attn_k(const ushort_t* __restrict__ qkv,
                                                 const ushort_t* __restrict__ vg,
                                                 ushort_t* __restrict__ y) {
  int t = threadIdx.x;
  int w = t >> 6, lane = t & 63;
  int lm = lane & 15, qq = lane >> 4;
  int q8 = qq * 8, q4 = qq * 4;
  int bh = blockIdx.x;
  int qt = (int)gridDim.y - 1 - (int)blockIdx.y;   // heavy q-tiles dispatch first
  int b = bh / H_, h = bh % H_;

  size_t baserow = (size_t)b * T_;
  const ushort_t* qkvb = qkv + baserow * C3_ + h * D_;
  const ushort_t* kbase = qkvb + C_;
  const ushort_t* vbase = vg + (size_t)bh * D_ * T_;

  int qrow0 = qt * 64 + w * 16;   // this wave's 16 q rows; lane's q = qrow0 + lm
  const ushort_t* qp = qkvb + (size_t)(qrow0 + lm) * C3_ + q8;
  bf16x8_t aq0 = *(const bf16x8_t*)(qp);        // Q B-frag: n=q, k=d
  bf16x8_t aq1 = *(const bf16x8_t*)(qp + 32);

  const f32x4 fz = {0.f, 0.f, 0.f, 0.f};
  f32x4 aO0 = fz, aO1 = fz, aO2 = fz, aO3 = fz;   // O^T per d-tile, C-layout (col=q)
  float lsum = 0.f;                               // lane's q-denominator

  const float SC = 0.125f * 1.44269504088896340736f;  // scale * log2(e)

#define BODY(KT, MASKED)                                                          \
  {                                                                               \
    const ushort_t* kp_ = kbase + (size_t)(KT) * 64 * C3_;                        \
    const ushort_t* vp_ = vbase + (KT) * 64 + q4;                                 \
    /* V^T A-frags: m=d(lane&15 within tile jd), k=key=quad*4+j -> 8B loads */    \
    short4_t vf[4][4];                                                            \
    _Pragma("unroll") for (int jd = 0; jd < 4; jd++)                              \
      _Pragma("unroll") for (int tt = 0; tt < 4; tt++)                            \
        vf[jd][tt] = *(const short4_t*)(vp_ + (size_t)(jd * 16 + lm) * T_ + tt * 16); \
    /* K A-frags: m=k_local(lane&15), k=d -> 16B loads */                         \
    bf16x8_t kf[4][2];                                                            \
    _Pragma("unroll") for (int tt = 0; tt < 4; tt++) {                            \
      kf[tt][0] = *(const bf16x8_t*)(kp_ + (size_t)(tt * 16 + lm) * C3_ + q8);    \
      kf[tt][1] = *(const bf16x8_t*)(kp_ + (size_t)(tt * 16 + lm) * C3_ + 32 + q8); \
    }                                                                             \
    /* S^T tiles: [k_local 16][q 16] */                                           \
    f32x4 sa[4];                                                                  \
    _Pragma("unroll") for (int tt = 0; tt < 4; tt++) {                            \
      sa[tt] = fz;                                                                \
      MFMA16(sa[tt], kf[tt][0], aq0);                                             \
      MFMA16(sa[tt], kf[tt][1], aq1);                                             \
    }                                                                             \
    /* softmax numerators, packed straight into PV B-operands */                  \
    short4_t pt[4];                                                               \
    _Pragma("unroll") for (int tt = 0; tt < 4; tt++) {                            \
      _Pragma("unroll") for (int r = 0; r < 4; r++) {                             \
        float v = sa[tt][r] * SC;                                                 \
        if (MASKED && (tt * 16 + q4 + r) > (w * 16 + lm)) v = -1e30f;             \
        float p = exp2f(v);                                                       \
        lsum += p;                                                                \
        pt[tt][r] = f2bf_trunc_s(p);                                              \
      }                                                                           \
    }                                                                             \
    /* O^T[d-tile] += V^T-frag * P^T (registers only) */                          \
    _Pragma("unroll") for (int tt = 0; tt < 4; tt++) {                            \
      MFMA16K16(aO0, vf[0][tt], pt[tt]);                                          \
      MFMA16K16(aO1, vf[1][tt], pt[tt]);                                          \
      MFMA16K16(aO2, vf[2][tt], pt[tt]);                                          \
      MFMA16K16(aO3, vf[3][tt], pt[tt]);                                          \
    }                                                                             \
  }

  for (int kt = 0; kt < qt; kt++) BODY(kt, false)
  BODY(qt, true)
#undef BODY

  // denominator: lane owns one q; sum over the 4 lane-quads
  float s = lsum;
  s += __shfl_xor(s, 16);
  s += __shfl_xor(s, 32);
  float inv = 1.f / s;

  // O^T C-layout: lane holds q=lm(col), d = jd*16 + qq*4 + r -> pack 4 -> 8B store
  size_t obase = (baserow + qrow0 + lm) * C_ + h * D_ + q4;
#define STO(AO, JD) { \
    short4_t o4; \
    o4[0] = (short)f2bf(AO[0] * inv); o4[1] = (short)f2bf(AO[1] * inv); \
    o4[2] = (short)f2bf(AO[2] * inv); o4[3] = (short)f2bf(AO[3] * inv); \
    *(short4_t*)(y + obase + (JD) * 16) = o4; }
  STO(aO0, 0) STO(aO1, 1) STO(aO2, 2) STO(aO3, 3)
#undef STO
}

extern "C" void kernel_launch(void* const* d_in, const int* in_sizes, int n_in,
                              void* d_out, int out_size, void* d_ws, size_t ws_size,
                              hipStream_t stream) {
  (void)in_sizes; (void)n_in; (void)out_size; (void)ws_size;
  const float* x      = (const float*)d_in[0];
  const float* ln1_g  = (const float*)d_in[1];
  const float* ln1_b  = (const float*)d_in[2];
  const float* W_attn = (const float*)d_in[3];
  const float* W_o    = (const float*)d_in[4];
  const float* ln2_g  = (const float*)d_in[5];
  const float* ln2_b  = (const float*)d_in[6];
  const float* W_fc   = (const float*)d_in[7];
  const float* W_proj = (const float*)d_in[8];

  char* ws = (char*)d_ws;
  ushort_t* big  = (ushort_t*)(ws);
  ushort_t* Vg   = (ushort_t*)(ws + 37748736);  // V^T [48][64][2048] bf16
  ushort_t* tmp  = (ushort_t*)(ws + 50331648);  // xhat1 / y / xhat2 (8192x768 bf16)
  float*    x2   = (float*)   (ws + 62914560);  // residual1 fp32 (8192x768)
  ushort_t* Wat  = (ushort_t*)(ws + 88080384);  // W_attn^T [2304,768] bf16
  ushort_t* Wot  = (ushort_t*)(ws + 91619328);  // W_o^T    [768,768]  bf16
  ushort_t* Wfct = (ushort_t*)(ws + 92798976);  // W_fc^T   [3072,768] bf16
  ushort_t* Wpt  = (ushort_t*)(ws + 97517568);  // W_proj^T [768,3072] bf16

  dim3 tb(32, 8);
  transpose_k<<<dim3(C3_ / 32, C_ / 32), tb, 0, stream>>>(W_attn, Wat, C_, C3_);
  transpose_k<<<dim3(C_ / 32, C_ / 32), tb, 0, stream>>>(W_o, Wot, C_, C_);
  transpose_k<<<dim3(HID_ / 32, C_ / 32), tb, 0, stream>>>(W_fc, Wfct, C_, HID_);
  transpose_k<<<dim3(C_ / 32, HID_ / 32), tb, 0, stream>>>(W_proj, Wpt, HID_, C_);

  ln_k<<<M_, 256, 0, stream>>>(x, ln1_g, ln1_b, tmp);
  gemm_bt_k<0><<<dim3(C3_ / 128, M_ / 128), 256, 0, stream>>>(tmp, Wat, nullptr, big, C3_, C_);
  vtrans_k<<<dim3(T_ / 32, D_ / 32, B_ * H_), tb, 0, stream>>>(big, Vg);
  attn_k<<<dim3(B_ * H_, T_ / 64), 256, 0, stream>>>(big, Vg, tmp);
  gemm_bt_k<1><<<dim3(C_ / 128, M_ / 128), 256, 0, stream>>>(tmp, Wot, x, x2, C_, C_);
  ln_k<<<M_, 256, 0, stream>>>(x2, ln2_g, ln2_b, tmp);
  gemm_bt_k<2><<<dim3(HID_ / 128, M_ / 128), 256, 0, stream>>>(tmp, Wfct, nullptr, big, HID_, C_);
  gemm_bt_k<1><<<dim3(C_ / 128, M_ / 128), 256, 0, stream>>>(big, Wpt, x2, d_out, C_, HID_);
}